// Round 1
// baseline (932.146 us; speedup 1.0000x reference)
//
#include <hip/hip_runtime.h>
#include <cstddef>

#define NN 50000          // number of nodes
#define WAVES_PER_BLOCK 4

// ---------------------------------------------------------------------------
// K1 (hipMemsetAsync): zero counts
// K2: histogram of edge destinations
// ---------------------------------------------------------------------------
__global__ void hist_kernel(const int* __restrict__ dst, int* __restrict__ counts, int E) {
    int i = blockIdx.x * blockDim.x + threadIdx.x;
    if (i < E) atomicAdd(&counts[dst[i]], 1);
}

// ---------------------------------------------------------------------------
// K3: single-block exclusive scan over counts -> offsets[N+1]; also init cursor
// ---------------------------------------------------------------------------
__global__ void scan_kernel(const int* __restrict__ counts, int* __restrict__ offsets,
                            int* __restrict__ cursor, int n) {
    const int T = 1024;
    int t = threadIdx.x;
    int chunk = (n + T - 1) / T;          // 49 for n=50000
    int begin = t * chunk;
    int end = begin + chunk; if (end > n) end = n;

    int s = 0;
    for (int i = begin; i < end; ++i) s += counts[i];

    __shared__ int sums[T];
    sums[t] = s;
    __syncthreads();
    // Hillis-Steele inclusive scan
    for (int off = 1; off < T; off <<= 1) {
        int v = (t >= off) ? sums[t - off] : 0;
        __syncthreads();
        sums[t] += v;
        __syncthreads();
    }
    int run = (t == 0) ? 0 : sums[t - 1]; // exclusive prefix for this chunk
    for (int i = begin; i < end; ++i) {
        offsets[i] = run;
        cursor[i]  = run;
        run += counts[i];
    }
    if (t == T - 1) offsets[n] = run;     // total = E
}

// ---------------------------------------------------------------------------
// K4: scatter edge ids into CSR order
// ---------------------------------------------------------------------------
__global__ void scatter_kernel(const int* __restrict__ dst, int* __restrict__ cursor,
                               int* __restrict__ sorted, int E) {
    int i = blockIdx.x * blockDim.x + threadIdx.x;
    if (i < E) {
        int d = dst[i];
        int pos = atomicAdd(&cursor[d], 1);
        sorted[pos] = i;
    }
}

// ---------------------------------------------------------------------------
// K5: one wave per node. lane = e_slot*8 + h  (8 edges x 8 heads per wave).
// Head h owns: deg0 channels 4h..4h+3 (1 x float4) and deg1 flat 12h..12h+11
// (3 x float4; 48h bytes is 16B aligned). Softmax without max subtraction
// (scores ~N(0,0.125); exp cannot overflow; softmax is shift-invariant).
// ---------------------------------------------------------------------------
__global__ __launch_bounds__(256) void attn_kernel(
    const float* __restrict__ q0, const float* __restrict__ q1,
    const float* __restrict__ k0, const float* __restrict__ k1,
    const float* __restrict__ v0, const float* __restrict__ v1,
    const int* __restrict__ offsets, const int* __restrict__ sorted,
    float* __restrict__ out)
{
    int wave = threadIdx.x >> 6;
    int node = blockIdx.x * WAVES_PER_BLOCK + wave;
    if (node >= NN) return;
    int lane = threadIdx.x & 63;
    int h  = lane & 7;
    int es = lane >> 3;

    // query fragment for this head (16 floats, same for all 8 e_slots)
    const float4 qa = *(const float4*)(q0 + (size_t)node * 32 + 4 * h);
    const float4* q1p = (const float4*)(q1 + (size_t)node * 96 + 12 * h);
    const float4 qb = q1p[0], qc = q1p[1], qd = q1p[2];

    int rs = offsets[node], re = offsets[node + 1];

    float acc[16];
#pragma unroll
    for (int j = 0; j < 16; ++j) acc[j] = 0.f;
    float l = 0.f;

    for (int base = rs; base < re; base += 8) {
        int ei = base + es;
        bool valid = ei < re;
        int e = sorted[valid ? ei : rs];   // clamp to a safe in-range index

        const float4 ka = *(const float4*)(k0 + (size_t)e * 32 + 4 * h);
        const float4* k1p = (const float4*)(k1 + (size_t)e * 96 + 12 * h);
        const float4 kb = k1p[0], kc = k1p[1], kd = k1p[2];

        float s = qa.x * ka.x + qa.y * ka.y + qa.z * ka.z + qa.w * ka.w
                + qb.x * kb.x + qb.y * kb.y + qb.z * kb.z + qb.w * kb.w
                + qc.x * kc.x + qc.y * kc.y + qc.z * kc.z + qc.w * kc.w
                + qd.x * kd.x + qd.y * kd.y + qd.z * kd.z + qd.w * kd.w;

        float w = valid ? __expf(s * 0.08838834764831845f) : 0.f; // 1/sqrt(128)
        l += w;

        const float4 va = *(const float4*)(v0 + (size_t)e * 32 + 4 * h);
        const float4* v1p = (const float4*)(v1 + (size_t)e * 96 + 12 * h);
        const float4 vb = v1p[0], vc = v1p[1], vd = v1p[2];

        acc[0]  += w * va.x; acc[1]  += w * va.y; acc[2]  += w * va.z; acc[3]  += w * va.w;
        acc[4]  += w * vb.x; acc[5]  += w * vb.y; acc[6]  += w * vb.z; acc[7]  += w * vb.w;
        acc[8]  += w * vc.x; acc[9]  += w * vc.y; acc[10] += w * vc.z; acc[11] += w * vc.w;
        acc[12] += w * vd.x; acc[13] += w * vd.y; acc[14] += w * vd.z; acc[15] += w * vd.w;
    }

    // reduce across the 8 e_slots (same h -> lanes differing in bits 3..5)
#pragma unroll
    for (int m = 8; m < 64; m <<= 1) {
        l += __shfl_xor(l, m, 64);
#pragma unroll
        for (int j = 0; j < 16; ++j) acc[j] += __shfl_xor(acc[j], m, 64);
    }

    if (es == 0) {
        float r = (l > 0.f) ? (1.0f / l) : 0.f;  // edge-less node -> zeros
        float4 o0; o0.x = acc[0] * r; o0.y = acc[1] * r; o0.z = acc[2] * r; o0.w = acc[3] * r;
        *(float4*)(out + (size_t)node * 32 + 4 * h) = o0;
        float* o1 = out + (size_t)NN * 32 + (size_t)node * 96 + 12 * h;
        float4 t0; t0.x = acc[4]  * r; t0.y = acc[5]  * r; t0.z = acc[6]  * r; t0.w = acc[7]  * r;
        float4 t1; t1.x = acc[8]  * r; t1.y = acc[9]  * r; t1.z = acc[10] * r; t1.w = acc[11] * r;
        float4 t2; t2.x = acc[12] * r; t2.y = acc[13] * r; t2.z = acc[14] * r; t2.w = acc[15] * r;
        ((float4*)o1)[0] = t0;
        ((float4*)o1)[1] = t1;
        ((float4*)o1)[2] = t2;
    }
}

// ---------------------------------------------------------------------------
extern "C" void kernel_launch(void* const* d_in, const int* in_sizes, int n_in,
                              void* d_out, int out_size, void* d_ws, size_t ws_size,
                              hipStream_t stream) {
    const float* q0 = (const float*)d_in[0];
    const float* q1 = (const float*)d_in[1];
    const float* k0 = (const float*)d_in[2];
    const float* k1 = (const float*)d_in[3];
    const float* v0 = (const float*)d_in[4];
    const float* v1 = (const float*)d_in[5];
    const int*  dst = (const int*)d_in[6];
    const int E = in_sizes[6];
    float* out = (float*)d_out;

    // workspace layout (ints): offsets[NN+1] | cursor[NN] | counts[NN] | sorted[E]
    int* offsets = (int*)d_ws;
    int* cursor  = offsets + (NN + 1);
    int* counts  = cursor + NN;
    int* sorted  = counts + NN;

    hipMemsetAsync(counts, 0, NN * sizeof(int), stream);
    hist_kernel<<<(E + 255) / 256, 256, 0, stream>>>(dst, counts, E);
    scan_kernel<<<1, 1024, 0, stream>>>(counts, offsets, cursor, NN);
    scatter_kernel<<<(E + 255) / 256, 256, 0, stream>>>(dst, cursor, sorted, E);
    attn_kernel<<<(NN + WAVES_PER_BLOCK - 1) / WAVES_PER_BLOCK, 256, 0, stream>>>(
        q0, q1, k0, k1, v0, v1, offsets, sorted, out);
}

// Round 2
// 795.456 us; speedup vs baseline: 1.1718x; 1.1718x over previous
//
#include <hip/hip_runtime.h>
#include <cstddef>

#define NN 50000          // number of nodes
#define WPB 4             // waves per block in attn kernel
#define SCAN_B 256
#define NB1 ((NN + SCAN_B - 1) / SCAN_B)   // 196 scan blocks

// ---------------------------------------------------------------------------
// block-wide inclusive scan (blockDim.x = 256 = 4 waves)
// ---------------------------------------------------------------------------
__device__ __forceinline__ int block_inc_scan(int x, int* lds) {
    int lane = threadIdx.x & 63;
    int wid  = threadIdx.x >> 6;
#pragma unroll
    for (int d = 1; d < 64; d <<= 1) {
        int v = __shfl_up(x, d, 64);
        if (lane >= d) x += v;
    }
    if (lane == 63) lds[wid] = x;
    __syncthreads();
    if (wid == 0 && lane < 4) {
        int s = lds[lane];
#pragma unroll
        for (int d = 1; d < 4; d <<= 1) {
            int v = __shfl_up(s, d, 64);
            if (lane >= d) s += v;
        }
        lds[lane] = s;
    }
    __syncthreads();
    if (wid > 0) x += lds[wid - 1];
    return x;
}

// ---------------------------------------------------------------------------
// K2: fused histogram + per-edge rank (only atomic pass: 800K atomics)
// ---------------------------------------------------------------------------
__global__ void hist_rank_kernel(const int* __restrict__ dst, int* __restrict__ counts,
                                 int* __restrict__ rank, int E) {
    int i = blockIdx.x * blockDim.x + threadIdx.x;
    if (i < E) {
        int d = dst[i];
        rank[i] = atomicAdd(&counts[d], 1);
    }
}

// ---------------------------------------------------------------------------
// K3a: per-block sums of counts (coalesced)
// ---------------------------------------------------------------------------
__global__ __launch_bounds__(SCAN_B) void scan_sum_kernel(const int* __restrict__ counts,
                                                          int* __restrict__ bsum) {
    __shared__ int lds[4];
    int i = blockIdx.x * SCAN_B + threadIdx.x;
    int c = (i < NN) ? counts[i] : 0;
    int inc = block_inc_scan(c, lds);
    if (threadIdx.x == SCAN_B - 1) bsum[blockIdx.x] = inc;
}

// K3b: single block scans the 196 block sums -> exclusive bases; offsets[NN]=E
__global__ __launch_bounds__(SCAN_B) void scan_base_kernel(const int* __restrict__ bsum,
                                                           int* __restrict__ bbase,
                                                           int* __restrict__ offsets) {
    __shared__ int lds[4];
    int t = threadIdx.x;
    int c = (t < NB1) ? bsum[t] : 0;
    int inc = block_inc_scan(c, lds);
    if (t < NB1) bbase[t] = inc - c;             // exclusive base of block t
    if (t == NB1 - 1) offsets[NN] = inc;         // total = E
}

// K3c: final offsets (coalesced block scan + base)
__global__ __launch_bounds__(SCAN_B) void scan_off_kernel(const int* __restrict__ counts,
                                                          const int* __restrict__ bbase,
                                                          int* __restrict__ offsets) {
    __shared__ int lds[4];
    int i = blockIdx.x * SCAN_B + threadIdx.x;
    int c = (i < NN) ? counts[i] : 0;
    int inc = block_inc_scan(c, lds);
    if (i < NN) offsets[i] = bbase[blockIdx.x] + inc - c;   // exclusive scan
}

// ---------------------------------------------------------------------------
// K4: atomic-free placement into CSR order (stable)
// ---------------------------------------------------------------------------
__global__ void place_kernel(const int* __restrict__ dst, const int* __restrict__ rank,
                             const int* __restrict__ offsets, int* __restrict__ sorted, int E) {
    int i = blockIdx.x * blockDim.x + threadIdx.x;
    if (i < E) {
        int d = dst[i];
        sorted[offsets[d] + rank[i]] = i;
    }
}

// ---------------------------------------------------------------------------
// K5: one wave per node. lane = e_slot*8 + h  (8 edges x 8 heads per wave).
// Head h owns: deg0 channels 4h..4h+3 (1 x float4) and deg1 flat 12h..12h+11
// (3 x float4; 48h bytes is 16B aligned). Softmax without max subtraction
// (scores ~N(0,0.125); exp cannot overflow; softmax is shift-invariant).
// ---------------------------------------------------------------------------
__global__ __launch_bounds__(256) void attn_kernel(
    const float* __restrict__ q0, const float* __restrict__ q1,
    const float* __restrict__ k0, const float* __restrict__ k1,
    const float* __restrict__ v0, const float* __restrict__ v1,
    const int* __restrict__ offsets, const int* __restrict__ sorted,
    float* __restrict__ out)
{
    int wave = threadIdx.x >> 6;
    int node = blockIdx.x * WPB + wave;
    if (node >= NN) return;
    int lane = threadIdx.x & 63;
    int h  = lane & 7;
    int es = lane >> 3;

    const float4 qa = *(const float4*)(q0 + (size_t)node * 32 + 4 * h);
    const float4* q1p = (const float4*)(q1 + (size_t)node * 96 + 12 * h);
    const float4 qb = q1p[0], qc = q1p[1], qd = q1p[2];

    int rs = offsets[node], re = offsets[node + 1];

    float acc[16];
#pragma unroll
    for (int j = 0; j < 16; ++j) acc[j] = 0.f;
    float l = 0.f;

    for (int base = rs; base < re; base += 8) {
        int ei = base + es;
        bool valid = ei < re;
        int e = sorted[valid ? ei : rs];

        const float4 ka = *(const float4*)(k0 + (size_t)e * 32 + 4 * h);
        const float4* k1p = (const float4*)(k1 + (size_t)e * 96 + 12 * h);
        const float4 kb = k1p[0], kc = k1p[1], kd = k1p[2];

        float s = qa.x * ka.x + qa.y * ka.y + qa.z * ka.z + qa.w * ka.w
                + qb.x * kb.x + qb.y * kb.y + qb.z * kb.z + qb.w * kb.w
                + qc.x * kc.x + qc.y * kc.y + qc.z * kc.z + qc.w * kc.w
                + qd.x * kd.x + qd.y * kd.y + qd.z * kd.z + qd.w * kd.w;

        float w = valid ? __expf(s * 0.08838834764831845f) : 0.f; // 1/sqrt(128)
        l += w;

        const float4 va = *(const float4*)(v0 + (size_t)e * 32 + 4 * h);
        const float4* v1p = (const float4*)(v1 + (size_t)e * 96 + 12 * h);
        const float4 vb = v1p[0], vc = v1p[1], vd = v1p[2];

        acc[0]  += w * va.x; acc[1]  += w * va.y; acc[2]  += w * va.z; acc[3]  += w * va.w;
        acc[4]  += w * vb.x; acc[5]  += w * vb.y; acc[6]  += w * vb.z; acc[7]  += w * vb.w;
        acc[8]  += w * vc.x; acc[9]  += w * vc.y; acc[10] += w * vc.z; acc[11] += w * vc.w;
        acc[12] += w * vd.x; acc[13] += w * vd.y; acc[14] += w * vd.z; acc[15] += w * vd.w;
    }

#pragma unroll
    for (int m = 8; m < 64; m <<= 1) {
        l += __shfl_xor(l, m, 64);
#pragma unroll
        for (int j = 0; j < 16; ++j) acc[j] += __shfl_xor(acc[j], m, 64);
    }

    if (es == 0) {
        float r = (l > 0.f) ? (1.0f / l) : 0.f;
        float4 o0; o0.x = acc[0] * r; o0.y = acc[1] * r; o0.z = acc[2] * r; o0.w = acc[3] * r;
        *(float4*)(out + (size_t)node * 32 + 4 * h) = o0;
        float* o1 = out + (size_t)NN * 32 + (size_t)node * 96 + 12 * h;
        float4 t0; t0.x = acc[4]  * r; t0.y = acc[5]  * r; t0.z = acc[6]  * r; t0.w = acc[7]  * r;
        float4 t1; t1.x = acc[8]  * r; t1.y = acc[9]  * r; t1.z = acc[10] * r; t1.w = acc[11] * r;
        float4 t2; t2.x = acc[12] * r; t2.y = acc[13] * r; t2.z = acc[14] * r; t2.w = acc[15] * r;
        ((float4*)o1)[0] = t0;
        ((float4*)o1)[1] = t1;
        ((float4*)o1)[2] = t2;
    }
}

// ---------------------------------------------------------------------------
extern "C" void kernel_launch(void* const* d_in, const int* in_sizes, int n_in,
                              void* d_out, int out_size, void* d_ws, size_t ws_size,
                              hipStream_t stream) {
    const float* q0 = (const float*)d_in[0];
    const float* q1 = (const float*)d_in[1];
    const float* k0 = (const float*)d_in[2];
    const float* k1 = (const float*)d_in[3];
    const float* v0 = (const float*)d_in[4];
    const float* v1 = (const float*)d_in[5];
    const int*  dst = (const int*)d_in[6];
    const int E = in_sizes[6];
    float* out = (float*)d_out;

    // ws layout (ints): offsets[NN+1] | counts[NN] | bsum[NB1] | bbase[NB1] | rank[E] | sorted[E]
    int* offsets = (int*)d_ws;
    int* counts  = offsets + (NN + 1);
    int* bsum    = counts + NN;
    int* bbase   = bsum + NB1;
    int* rank    = bbase + NB1;
    int* sorted  = rank + E;

    hipMemsetAsync(counts, 0, NN * sizeof(int), stream);
    hist_rank_kernel<<<(E + 255) / 256, 256, 0, stream>>>(dst, counts, rank, E);
    scan_sum_kernel<<<NB1, SCAN_B, 0, stream>>>(counts, bsum);
    scan_base_kernel<<<1, SCAN_B, 0, stream>>>(bsum, bbase, offsets);
    scan_off_kernel<<<NB1, SCAN_B, 0, stream>>>(counts, bbase, offsets);
    place_kernel<<<(E + 255) / 256, 256, 0, stream>>>(dst, rank, offsets, sorted, E);
    attn_kernel<<<(NN + WPB - 1) / WPB, 256, 0, stream>>>(
        q0, q1, k0, k1, v0, v1, offsets, sorted, out);
}